// Round 10
// baseline (110.624 us; speedup 1.0000x reference)
//
#include <hip/hip_runtime.h>
#include <hip/hip_bf16.h>

#define NN 4096
#define NFEAT 256
#define NHID1 64
#define NHID2 32
#define NCLASS 8
#define NHEADS 4
#define NADJ 2
#define CAP 128

// f32 -> bf16 round-to-nearest-even
__device__ __forceinline__ unsigned short f2bf(float v) {
  unsigned int x = __float_as_uint(v);
  return (unsigned short)((x + 0x7fffu + ((x >> 16) & 1u)) >> 16);
}

// ---------------------------------------------------------------------------
// Register-blocked tiled GEMM body (k1): C = A @ B (bf16 out), fused attention
// coefficients from the f32 accumulators.
template <int KDIM, int NDIM, int RPTY>
__device__ __forceinline__ void gemm_body(
    const float* __restrict__ A, const float* __restrict__ B,
    unsigned short* __restrict__ C, const float* __restrict__ ag,
    float* __restrict__ fsrc, float* __restrict__ fdst, const int row0b,
    float* __restrict__ sA, float* __restrict__ sB) {
  constexpr int KT = 32;
  constexpr int TX = NDIM / 4;
  constexpr int TY = 256 / TX;
  constexpr int BR = TY * RPTY;
  constexpr int LDA = BR + 4;
  constexpr int LDB = NDIM + 4;
  const int tid = threadIdx.x;
  const int tx = tid % TX, ty = tid / TX;
  const int c0 = tx * 4;
  float acc[RPTY][4];
#pragma unroll
  for (int i = 0; i < RPTY; ++i)
#pragma unroll
    for (int j = 0; j < 4; ++j) acc[i][j] = 0.f;

  for (int kt = 0; kt < KDIM; kt += KT) {
    __syncthreads();
    for (int i = tid; i < BR * (KT / 4); i += 256) {
      const int r = i / (KT / 4), e = i % (KT / 4);
      const float4 v = *(const float4*)(A + (size_t)(row0b + r) * KDIM + kt + e * 4);
      sA[(e * 4 + 0) * LDA + r] = v.x;
      sA[(e * 4 + 1) * LDA + r] = v.y;
      sA[(e * 4 + 2) * LDA + r] = v.z;
      sA[(e * 4 + 3) * LDA + r] = v.w;
    }
    for (int i = tid; i < KT * (NDIM / 4); i += 256) {
      const int k = i / (NDIM / 4), cc = i % (NDIM / 4);
      *(float4*)&sB[k * LDB + cc * 4] = *(const float4*)(B + (size_t)(kt + k) * NDIM + cc * 4);
    }
    __syncthreads();
#pragma unroll
    for (int k = 0; k < KT; ++k) {
      const float4 t = *(const float4*)&sA[k * LDA + ty * 4];
      const float a4[4] = {t.x, t.y, t.z, t.w};
      const float4 bv = *(const float4*)&sB[k * LDB + c0];
      const float b4[4] = {bv.x, bv.y, bv.z, bv.w};
#pragma unroll
      for (int i = 0; i < RPTY; ++i)
#pragma unroll
        for (int j = 0; j < 4; ++j) acc[i][j] += a4[i] * b4[j];
    }
  }
#pragma unroll
  for (int i = 0; i < RPTY; ++i) {
    const int row = row0b + ty * RPTY + i;
    ushort4 o;
    o.x = f2bf(acc[i][0]); o.y = f2bf(acc[i][1]);
    o.z = f2bf(acc[i][2]); o.w = f2bf(acc[i][3]);
    *(ushort4*)(C + (size_t)row * NDIM + c0) = o;
  }
  float aS[4], aD[4];
#pragma unroll
  for (int j = 0; j < 4; ++j) { aS[j] = ag[c0 + j]; aD[j] = ag[NDIM + c0 + j]; }
#pragma unroll
  for (int i = 0; i < RPTY; ++i) {
    float s = 0.f, d = 0.f;
#pragma unroll
    for (int j = 0; j < 4; ++j) { s += acc[i][j] * aS[j]; d += acc[i][j] * aD[j]; }
#pragma unroll
    for (int off = TX / 2; off; off >>= 1) {
      s += __shfl_xor(s, off);
      d += __shfl_xor(d, off);
    }
    if (tx == 0) {
      const int row = row0b + ty * RPTY + i;
      fsrc[row] = s;
      fdst[row] = d;
    }
  }
}

// ---------------------------------------------------------------------------
// K1: blocks [0,512) = L1 GAT GEMM (+coef1, bf16 Wh1); rest = edge build.
__global__ __launch_bounds__(256) void k1_gemm_edges(
    const float* __restrict__ x, const float* __restrict__ W1,
    const float* __restrict__ a1, unsigned short* __restrict__ Wh1,
    float* __restrict__ fs1, float* __restrict__ fd1,
    const float* __restrict__ adj, int* __restrict__ eidx,
    int* __restrict__ ecnt) {
  __shared__ float sA[32 * (64 + 4)];
  __shared__ float sB[32 * (64 + 4)];
  constexpr int NB_GEMM = (NN / 64) * NHEADS * NADJ;  // 512
  if (blockIdx.x < NB_GEMM) {
    int b = blockIdx.x;
    const int tile = b % (NN / 64); b /= (NN / 64);
    const int h = b % NHEADS;
    const int g = b / NHEADS;
    const int gh = g * NHEADS + h;
    gemm_body<NFEAT, NHID1, 4>(
        x, W1 + (size_t)gh * NFEAT * NHID1, Wh1 + (size_t)gh * NN * NHID1,
        a1 + (size_t)gh * 2 * NHID1, fs1 + (size_t)gh * NN,
        fd1 + (size_t)gh * NN, tile * 64, sA, sB);
  } else {
    const int wave = threadIdx.x >> 6;
    const int lane = threadIdx.x & 63;
    const int r = (blockIdx.x - NB_GEMM) * 4 + wave;  // g*NN + n
    const float4* row = (const float4*)(adj + (size_t)r * NN);
    int* out = eidx + (size_t)r * CAP;
    int base = 0;
    for (int c = 0; c < NN; c += 256) {
      const float4 v = row[(c >> 2) + lane];
      const int j0 = c + lane * 4;
      const float vt[4] = {v.x, v.y, v.z, v.w};
#pragma unroll
      for (int t = 0; t < 4; ++t) {
        const bool hit = vt[t] > 0.f;
        const unsigned long long m = __ballot(hit);
        if (hit) {
          const int pos = base + __popcll(m & ((1ull << lane) - 1ull));
          if (pos < CAP) out[pos] = j0 + t;
        }
        base += __popcll(m);
      }
    }
    if (lane == 0) ecnt[r] = base < CAP ? base : CAP;
  }
}

// ---------------------------------------------------------------------------
// L1 aggregate: sparse masked softmax + aggregation + ELU, one (n,h,g)/wave.
// Gather reads bf16 Wh (uint4 = 8 channels / lane).
#define GATB(ACC, JJ, OO)                                                      \
  {                                                                            \
    const float w_ = wgt[wave][JJ];                                            \
    const uint4 v_ = *(const uint4*)(WhH + (size_t)midx[wave][JJ] * OO + c8);  \
    ACC[0] += w_ * __uint_as_float(v_.x << 16);                                \
    ACC[1] += w_ * __uint_as_float(v_.x & 0xffff0000u);                        \
    ACC[2] += w_ * __uint_as_float(v_.y << 16);                                \
    ACC[3] += w_ * __uint_as_float(v_.y & 0xffff0000u);                        \
    ACC[4] += w_ * __uint_as_float(v_.z << 16);                                \
    ACC[5] += w_ * __uint_as_float(v_.z & 0xffff0000u);                        \
    ACC[6] += w_ * __uint_as_float(v_.w << 16);                                \
    ACC[7] += w_ * __uint_as_float(v_.w & 0xffff0000u);                        \
  }

__global__ __launch_bounds__(256) void aggregate1(
    const unsigned short* __restrict__ Wh, const float* __restrict__ fsrc,
    const float* __restrict__ fdst, const int* __restrict__ eidx,
    const int* __restrict__ ecnt, float* __restrict__ Hout) {
  constexpr int O = NHID1;       // 64
  constexpr int CPL = O / 8;     // 8 lanes per edge row
  constexpr int EPW = 64 / CPL;  // 8 edges in parallel
  __shared__ float wgt[4][CAP];
  __shared__ int midx[4][CAP];
  const int wave = threadIdx.x >> 6;
  const int lane = threadIdx.x & 63;
  const int n = blockIdx.x * 4 + wave;
  const int h = blockIdx.y, g = blockIdx.z;
  const int gh = g * NHEADS + h;
  const int cnt = ecnt[(size_t)g * NN + n];
  const int* ei = eidx + (size_t)(g * NN + n) * CAP;
  const float fs = fsrc[(size_t)gh * NN + n];
  const float* fd = fdst + (size_t)gh * NN;
  float mx = -3.4e38f;
  for (int j = lane; j < cnt; j += 64) {
    const int m = ei[j];
    float e = fs + fd[m];
    e = e > 0.f ? e : 0.2f * e;  // leaky relu alpha=0.2
    midx[wave][j] = m;
    wgt[wave][j] = e;
    mx = fmaxf(mx, e);
  }
  for (int off = 32; off; off >>= 1) mx = fmaxf(mx, __shfl_xor(mx, off));
  float sm = 0.f;
  for (int j = lane; j < cnt; j += 64) {
    const float w = __expf(wgt[wave][j] - mx);
    wgt[wave][j] = w;
    sm += w;
  }
  for (int off = 32; off; off >>= 1) sm += __shfl_xor(sm, off);
  const unsigned short* WhH = Wh + (size_t)gh * NN * O;
  const int sub = lane / CPL;
  const int c8 = (lane % CPL) * 8;
  float A0[8] = {0, 0, 0, 0, 0, 0, 0, 0};
  float A1[8] = {0, 0, 0, 0, 0, 0, 0, 0};
  int j = sub;
  for (; j + EPW < cnt; j += 2 * EPW) {
    GATB(A0, j, O);
    GATB(A1, j + EPW, O);
  }
  for (; j < cnt; j += EPW) GATB(A0, j, O);
#pragma unroll
  for (int q = 0; q < 8; ++q) A0[q] += A1[q];
#pragma unroll
  for (int off = CPL; off < 64; off <<= 1)
#pragma unroll
    for (int q = 0; q < 8; ++q) A0[q] += __shfl_xor(A0[q], off);
  if (lane < CPL) {
    const float inv = 1.f / sm;
    float o[8];
#pragma unroll
    for (int q = 0; q < 8; ++q) {
      o[q] = A0[q] * inv;
      o[q] = o[q] > 0.f ? o[q] : (__expf(o[q]) - 1.f);  // elu
    }
    float* dst = Hout + (size_t)g * NN * (NHEADS * O) + (size_t)n * (NHEADS * O) +
                 h * O + lane * 8;
    float4 o0, o1;
    o0.x = o[0]; o0.y = o[1]; o0.z = o[2]; o0.w = o[3];
    o1.x = o[4]; o1.y = o[5]; o1.z = o[6]; o1.w = o[7];
    *(float4*)dst = o0;
    *(float4*)(dst + 4) = o1;
  }
}

// ---------------------------------------------------------------------------
// K3: interlayer GEMM + L2 GAT GEMM + coef2 fused (GEMM->GEMM through LDS).
// Block = 32 rows of graph g. Phase 1: x1s = elu(h1[rows]@Wi1+bi1) (K-tiled).
// Phase 2: Wh2 = x1s @ W2[g,h] for 4 heads (W2 staged), coef2 via shfl fold.
__global__ __launch_bounds__(256) void k3_inter_gemm2(
    const float* __restrict__ h1, const float* __restrict__ Wi1,
    const float* __restrict__ bi1, const float* __restrict__ W2,
    const float* __restrict__ a2, unsigned short* __restrict__ Wh2,
    float* __restrict__ fs2, float* __restrict__ fd2) {
  __shared__ float sA[32 * 36];            // A tile transposed [k][row]
  __shared__ float sB[32 * 68];            // Wi1 tile [k][c]
  __shared__ float x1s[32 * 68];           // x1 rows [row][c]
  __shared__ float W2s[NHEADS * 64 * 32];  // 32 KB, all 4 heads
  const int g = blockIdx.y;
  const int n0 = blockIdx.x * 32;
  const int tid = threadIdx.x;
  const float* A = h1 + (size_t)g * NN * (NHEADS * NHID1);

  // ---- Phase 1: x1 = elu(A @ Wi1 + bi1), 32 rows x 64 cols
  const int tx = tid & 15, ty = tid >> 4;
  const int c0 = tx * 4;
  float acc[2][4] = {{0.f, 0.f, 0.f, 0.f}, {0.f, 0.f, 0.f, 0.f}};
  for (int kt = 0; kt < 256; kt += 32) {
    __syncthreads();
    for (int i = tid; i < 32 * 8; i += 256) {
      const int r = i >> 3, e = i & 7;
      const float4 v = *(const float4*)(A + (size_t)(n0 + r) * 256 + kt + e * 4);
      sA[(e * 4 + 0) * 36 + r] = v.x;
      sA[(e * 4 + 1) * 36 + r] = v.y;
      sA[(e * 4 + 2) * 36 + r] = v.z;
      sA[(e * 4 + 3) * 36 + r] = v.w;
    }
    for (int i = tid; i < 32 * 16; i += 256) {
      const int k = i >> 4, cc = i & 15;
      *(float4*)&sB[k * 68 + cc * 4] = *(const float4*)(Wi1 + (size_t)(kt + k) * 64 + cc * 4);
    }
    __syncthreads();
#pragma unroll
    for (int k = 0; k < 32; ++k) {
      const float2 t = *(const float2*)&sA[k * 36 + ty * 2];
      const float4 bv = *(const float4*)&sB[k * 68 + c0];
      const float b4[4] = {bv.x, bv.y, bv.z, bv.w};
#pragma unroll
      for (int j = 0; j < 4; ++j) {
        acc[0][j] += t.x * b4[j];
        acc[1][j] += t.y * b4[j];
      }
    }
  }
  {
    const float4 bb = *(const float4*)&bi1[c0];
    const float b4[4] = {bb.x, bb.y, bb.z, bb.w};
#pragma unroll
    for (int i = 0; i < 2; ++i) {
      float4 o;
      float* op = (float*)&o;
#pragma unroll
      for (int j = 0; j < 4; ++j) {
        float v = acc[i][j] + b4[j];
        op[j] = v > 0.f ? v : (__expf(v) - 1.f);  // elu
      }
      *(float4*)&x1s[(ty * 2 + i) * 68 + c0] = o;
    }
  }
  // stage all W2 heads for this graph
  {
    const float4* w2p = (const float4*)(W2 + (size_t)g * NHEADS * NHID1 * NHID2);
    for (int i = tid; i < 2048; i += 256) ((float4*)W2s)[i] = w2p[i];
  }
  __syncthreads();

  // ---- Phase 2: per head, Wh2 = x1s @ W2[h]; coef2 in-register
  const int c = tid & 31, rg = tid >> 5;  // 8 row-groups x 4 rows, 32 cols
  for (int h = 0; h < NHEADS; ++h) {
    const int gh = g * NHEADS + h;
    float a4[4] = {0.f, 0.f, 0.f, 0.f};
    for (int k = 0; k < 64; ++k) {
      const float w = W2s[(h * 64 + k) * 32 + c];
#pragma unroll
      for (int i = 0; i < 4; ++i) a4[i] += x1s[(rg * 4 + i) * 68 + k] * w;
    }
    const float* ag = a2 + (size_t)gh * 2 * NHID2;
    const float aS = ag[c], aD = ag[NHID2 + c];
#pragma unroll
    for (int i = 0; i < 4; ++i) {
      const int row = n0 + rg * 4 + i;
      Wh2[((size_t)gh * NN + row) * NHID2 + c] = f2bf(a4[i]);
      float s = a4[i] * aS, d = a4[i] * aD;
#pragma unroll
      for (int off = 16; off; off >>= 1) {
        s += __shfl_xor(s, off);
        d += __shfl_xor(d, off);
      }
      if (c == 0) {
        fs2[(size_t)gh * NN + row] = s;
        fd2[(size_t)gh * NN + row] = d;
      }
    }
  }
}

// ---------------------------------------------------------------------------
// K4: L2 aggregate + Wi2 + concat + Wf + log_softmax + l1. Block = 2 rows,
// 8 waves = (g,h); each wave does its (g,h) for both rows serially.
__global__ __launch_bounds__(512) void k4_agg2_tail(
    const unsigned short* __restrict__ Wh2, const float* __restrict__ fs2,
    const float* __restrict__ fd2, const int* __restrict__ eidx,
    const int* __restrict__ ecnt, const float* __restrict__ Wi2,
    const float* __restrict__ bi2, const float* __restrict__ Wf,
    const float* __restrict__ bfv, float* __restrict__ out) {
  constexpr int O = NHID2;  // 32
  __shared__ float Wi2s[128 * 8];
  __shared__ float WfS[16 * 8];
  __shared__ float h2cat[2][260];
  __shared__ float cat[2][17];
  __shared__ float wgt[8][CAP];
  __shared__ int midx[2][2][CAP];
  const int n0 = blockIdx.x * 2;
  const int tid = threadIdx.x;
  const int wave = tid >> 6;
  const int lane = tid & 63;

  for (int i = tid; i < 256; i += 512) ((float4*)Wi2s)[i] = ((const float4*)Wi2)[i];
  if (tid < 32) ((float4*)WfS)[tid] = ((const float4*)Wf)[tid];
  for (int i = tid; i < 4 * CAP; i += 512) {
    const int g_ = i >> 8, rr = (i >> 7) & 1, j = i & (CAP - 1);
    midx[g_][rr][j] = eidx[(size_t)(g_ * NN + n0 + rr) * CAP + j];
  }
  __syncthreads();

  // ---- Phase A: wave = (g,h); rows n0, n0+1 serially
  const int g = wave >> 2, h = wave & 3;
  const int gh = g * NHEADS + h;
  const unsigned short* WhH = Wh2 + (size_t)gh * NN * O;
  const float* fdv = fd2 + (size_t)gh * NN;
  for (int rr = 0; rr < 2; ++rr) {
    const int n = n0 + rr;
    const int cnt = ecnt[g * NN + n];
    const float fsv = fs2[(size_t)gh * NN + n];
    float mx = -3.4e38f;
    for (int j = lane; j < cnt; j += 64) {
      float e = fsv + fdv[midx[g][rr][j]];
      e = e > 0.f ? e : 0.2f * e;
      wgt[wave][j] = e;
      mx = fmaxf(mx, e);
    }
    for (int off = 32; off; off >>= 1) mx = fmaxf(mx, __shfl_xor(mx, off));
    float sm = 0.f;
    for (int j = lane; j < cnt; j += 64) {
      const float w = __expf(wgt[wave][j] - mx);
      wgt[wave][j] = w;
      sm += w;
    }
    for (int off = 32; off; off >>= 1) sm += __shfl_xor(sm, off);
    // gather: 4 lanes/edge (uint4 = 8 bf16), 16 edges in parallel, x2 unroll
    const int sub = lane >> 2;
    const int c8 = (lane & 3) * 8;
    float A0[8] = {0, 0, 0, 0, 0, 0, 0, 0};
    float A1[8] = {0, 0, 0, 0, 0, 0, 0, 0};
    {
      const int wv = wave;  // alias for GATB macro (uses wgt[wave], midx via mi)
      const int* mi = midx[g][rr];
      int j = sub;
      for (; j + 16 < cnt; j += 32) {
        {
          const float w_ = wgt[wv][j];
          const uint4 v_ = *(const uint4*)(WhH + (size_t)mi[j] * O + c8);
          A0[0] += w_ * __uint_as_float(v_.x << 16);
          A0[1] += w_ * __uint_as_float(v_.x & 0xffff0000u);
          A0[2] += w_ * __uint_as_float(v_.y << 16);
          A0[3] += w_ * __uint_as_float(v_.y & 0xffff0000u);
          A0[4] += w_ * __uint_as_float(v_.z << 16);
          A0[5] += w_ * __uint_as_float(v_.z & 0xffff0000u);
          A0[6] += w_ * __uint_as_float(v_.w << 16);
          A0[7] += w_ * __uint_as_float(v_.w & 0xffff0000u);
        }
        {
          const float w_ = wgt[wv][j + 16];
          const uint4 v_ = *(const uint4*)(WhH + (size_t)mi[j + 16] * O + c8);
          A1[0] += w_ * __uint_as_float(v_.x << 16);
          A1[1] += w_ * __uint_as_float(v_.x & 0xffff0000u);
          A1[2] += w_ * __uint_as_float(v_.y << 16);
          A1[3] += w_ * __uint_as_float(v_.y & 0xffff0000u);
          A1[4] += w_ * __uint_as_float(v_.z << 16);
          A1[5] += w_ * __uint_as_float(v_.z & 0xffff0000u);
          A1[6] += w_ * __uint_as_float(v_.w << 16);
          A1[7] += w_ * __uint_as_float(v_.w & 0xffff0000u);
        }
      }
      for (; j < cnt; j += 16) {
        const float w_ = wgt[wv][j];
        const uint4 v_ = *(const uint4*)(WhH + (size_t)mi[j] * O + c8);
        A0[0] += w_ * __uint_as_float(v_.x << 16);
        A0[1] += w_ * __uint_as_float(v_.x & 0xffff0000u);
        A0[2] += w_ * __uint_as_float(v_.y << 16);
        A0[3] += w_ * __uint_as_float(v_.y & 0xffff0000u);
        A0[4] += w_ * __uint_as_float(v_.z << 16);
        A0[5] += w_ * __uint_as_float(v_.z & 0xffff0000u);
        A0[6] += w_ * __uint_as_float(v_.w << 16);
        A0[7] += w_ * __uint_as_float(v_.w & 0xffff0000u);
      }
    }
#pragma unroll
    for (int q = 0; q < 8; ++q) A0[q] += A1[q];
#pragma unroll
    for (int off = 4; off < 64; off <<= 1)
#pragma unroll
      for (int q = 0; q < 8; ++q) A0[q] += __shfl_xor(A0[q], off);
    if (lane < 4) {
      const float inv = 1.f / sm;
      float o[8];
#pragma unroll
      for (int q = 0; q < 8; ++q) {
        o[q] = A0[q] * inv;
        o[q] = o[q] > 0.f ? o[q] : (__expf(o[q]) - 1.f);  // elu
      }
      float4 o0, o1;
      o0.x = o[0]; o0.y = o[1]; o0.z = o[2]; o0.w = o[3];
      o1.x = o[4]; o1.y = o[5]; o1.z = o[6]; o1.w = o[7];
      float* dst = &h2cat[rr][g * 128 + h * O + (lane & 3) * 8];
      *(float4*)dst = o0;
      *(float4*)(dst + 4) = o1;
    }
  }
  __syncthreads();

  // ---- Phase B: cat = elu(h2cat @ Wi2 + bi2); 2r x 2g x 8c x 16kc
  {
    const int r = tid >> 8, gg = (tid >> 7) & 1, c = (tid >> 4) & 7, kc = tid & 15;
    float s = 0.f;
#pragma unroll
    for (int k = kc * 8; k < kc * 8 + 8; ++k)
      s += h2cat[r][gg * 128 + k] * Wi2s[k * 8 + c];
#pragma unroll
    for (int off = 8; off; off >>= 1) s += __shfl_xor(s, off);
    if (kc == 0) {
      const float v = s + bi2[c];
      cat[r][gg * 8 + c] = v > 0.f ? v : (__expf(v) - 1.f);
    }
  }
  __syncthreads();

  // ---- Phase C: logits + log_softmax
  if (tid < 16) {
    const int r = tid >> 3, c = tid & 7;
    float logit = bfv[c];
#pragma unroll
    for (int k = 0; k < 16; ++k) logit += cat[r][k] * WfS[k * 8 + c];
    float m = logit;
#pragma unroll
    for (int off = 4; off; off >>= 1) m = fmaxf(m, __shfl_xor(m, off));
    float s = __expf(logit - m);
#pragma unroll
    for (int off = 4; off; off >>= 1) s += __shfl_xor(s, off);
    out[(size_t)(n0 + r) * NCLASS + c] = logit - (logf(s) + m);
  }
  if (blockIdx.x == 0 && tid >= 64 && tid < 128) {
    const int t = tid - 64;
    float v = fabsf(Wf[t]) + fabsf(Wf[64 + t]);
    for (int off = 32; off; off >>= 1) v += __shfl_xor(v, off);
    if (t == 0) out[NN * NCLASS] = v * (1.f / (2 * NCLASS * NCLASS));
  }
}

// ---------------------------------------------------------------------------
extern "C" void kernel_launch(void* const* d_in, const int* in_sizes, int n_in,
                              void* d_out, int out_size, void* d_ws, size_t ws_size,
                              hipStream_t stream) {
  const float* x = (const float*)d_in[0];
  const float* adj = (const float*)d_in[1];
  const float* W1 = (const float*)d_in[2];
  const float* a1 = (const float*)d_in[3];
  const float* W2 = (const float*)d_in[4];
  const float* a2 = (const float*)d_in[5];
  const float* Wi1 = (const float*)d_in[6];
  const float* bi1 = (const float*)d_in[7];
  const float* Wi2 = (const float*)d_in[8];
  const float* bi2 = (const float*)d_in[9];
  const float* Wf = (const float*)d_in[10];
  const float* bfv = (const float*)d_in[11];
  float* out = (float*)d_out;

  char* ws = (char*)d_ws;
  int* eidx = (int*)ws;            ws += (size_t)NADJ * NN * CAP * 4;            // 4 MB
  int* ecnt = (int*)ws;            ws += (size_t)NADJ * NN * 4;
  unsigned short* Wh1 = (unsigned short*)ws;
  ws += (size_t)NADJ * NHEADS * NN * NHID1 * 2;                                   // 4 MB
  float* fs1 = (float*)ws;         ws += (size_t)NADJ * NHEADS * NN * 4;
  float* fd1 = (float*)ws;         ws += (size_t)NADJ * NHEADS * NN * 4;
  float* h1 = (float*)ws;          ws += (size_t)NADJ * NN * NHEADS * NHID1 * 4;  // 8 MB
  unsigned short* Wh2 = (unsigned short*)ws;
  ws += (size_t)NADJ * NHEADS * NN * NHID2 * 2;                                   // 2 MB
  float* fs2 = (float*)ws;         ws += (size_t)NADJ * NHEADS * NN * 4;
  float* fd2 = (float*)ws;         ws += (size_t)NADJ * NHEADS * NN * 4;

  // K1: L1 GEMM (+coef1, bf16 out) overlapped with edge-list build.
  k1_gemm_edges<<<512 + NADJ * NN / 4, 256, 0, stream>>>(
      x, W1, a1, Wh1, fs1, fd1, adj, eidx, ecnt);

  // K2: L1 aggregate (bf16 gather).
  aggregate1<<<dim3(NN / 4, NHEADS, NADJ), 256, 0, stream>>>(
      Wh1, fs1, fd1, eidx, ecnt, h1);

  // K3: interlayer + L2 GEMM + coef2 (GEMM->GEMM fusion).
  k3_inter_gemm2<<<dim3(NN / 32, NADJ), 256, 0, stream>>>(
      h1, Wi1, bi1, W2, a2, Wh2, fs2, fd2);

  // K4: L2 aggregate + Wi2 + concat + Wf + log_softmax + l1.
  k4_agg2_tail<<<NN / 2, 512, 0, stream>>>(
      Wh2, fs2, fd2, eidx, ecnt, Wi2, bi2, Wf, bfv, out);
}